// Round 1
// baseline (2996.361 us; speedup 1.0000x reference)
//
#include <hip/hip_runtime.h>
#include <math.h>

#define E_DIM 512
#define H_DIM 512
#define V_DIM 32000
#define B_DIM 64
#define T_DIM 32

// ---------------------------------------------------------------------------
// Gather kernel: x0[m=b*T+t][:] = (t==0) ? features[b] : emb[sentence[b][t-1]]
// ---------------------------------------------------------------------------
__global__ __launch_bounds__(128) void build_x(const int* __restrict__ sent,
                                               const float* __restrict__ feat,
                                               const float* __restrict__ emb,
                                               float* __restrict__ x0) {
    int m = blockIdx.x;            // b*T + t
    int b = m >> 5, t = m & 31;
    const float* src = (t == 0) ? (feat + b * E_DIM)
                                : (emb + (long long)sent[b * T_DIM + t - 1] * E_DIM);
    float4 v = ((const float4*)src)[threadIdx.x];
    ((float4*)(x0 + (size_t)m * E_DIM))[threadIdx.x] = v;
}

// ---------------------------------------------------------------------------
// fp32 128x128 tiled GEMM, K=512. A[M][512] row-major, Bw[N][512] row-major
// (i.e. computes A @ Bw^T).
// MODE 0 (XP): C[m*N + n] = acc + bias1[n] + bias2[n]
// MODE 1 (FC): C[(b*V + v)*T + t] = acc + bias1[v]  with m=(b,t), n=v
// Lane->dim mapping flipped per MODE so stores are coalesced on the fast axis.
// ---------------------------------------------------------------------------
template <int MODE>
__global__ __launch_bounds__(256) void gemm128(const float* __restrict__ A,
                                               const float* __restrict__ Bw,
                                               const float* __restrict__ bias1,
                                               const float* __restrict__ bias2,
                                               float* __restrict__ C, int N_) {
    __shared__ float As[16][129];
    __shared__ float Bs[16][129];
    const int tid = threadIdx.x;
    const int tx = tid & 15, ty = tid >> 4;
    const int mtile = blockIdx.x * 128, ntile = blockIdx.y * 128;
    // MODE 0: stores need lanes on n  -> ni = tx
    // MODE 1: stores need lanes on m(t) -> mi = tx
    const int mi = MODE ? tx : ty;
    const int ni = MODE ? ty : tx;
    float acc[8][8] = {};
    const int lcol = tid & 15;   // k within chunk
    const int lrow = tid >> 4;   // row base

    for (int kc = 0; kc < 512; kc += 16) {
#pragma unroll
        for (int rr = 0; rr < 8; ++rr) {
            int row = lrow + 16 * rr;
            As[lcol][row] = A[(size_t)(mtile + row) * 512 + kc + lcol];
            Bs[lcol][row] = Bw[(size_t)(ntile + row) * 512 + kc + lcol];
        }
        __syncthreads();
#pragma unroll
        for (int k = 0; k < 16; ++k) {
            float a[8], bfr[8];
#pragma unroll
            for (int i = 0; i < 8; ++i) a[i] = As[k][mi + 16 * i];
#pragma unroll
            for (int j = 0; j < 8; ++j) bfr[j] = Bs[k][ni + 16 * j];
#pragma unroll
            for (int i = 0; i < 8; ++i)
#pragma unroll
                for (int j = 0; j < 8; ++j) acc[i][j] += a[i] * bfr[j];
        }
        __syncthreads();
    }

    if (MODE == 0) {
#pragma unroll
        for (int i = 0; i < 8; ++i) {
            int m = mtile + mi + 16 * i;
#pragma unroll
            for (int j = 0; j < 8; ++j) {
                int n = ntile + ni + 16 * j;
                C[(size_t)m * N_ + n] = acc[i][j] + bias1[n] + bias2[n];
            }
        }
    } else {
#pragma unroll
        for (int i = 0; i < 8; ++i) {
            int m = mtile + mi + 16 * i;
            int b = m >> 5, t = m & 31;
#pragma unroll
            for (int j = 0; j < 8; ++j) {
                int v = ntile + ni + 16 * j;
                C[(size_t)(b * V_DIM + v) * T_DIM + t] = acc[i][j] + bias1[v];
            }
        }
    }
}

// ---------------------------------------------------------------------------
// One LSTM timestep: gates = xp[:,t,:] + h_in @ Whh^T, then cell update.
// Grid (4 b-tiles of 16, 32 j-tiles of 16), 256 threads.
// Thread (bb,jj) owns (b, j) and computes all 4 gate dots (i,f,g,o).
// h double-buffered across launches (cross-WG RAW hazard otherwise).
// c is read+written only by its owning thread -> single buffer fine.
// ---------------------------------------------------------------------------
__global__ __launch_bounds__(256) void lstm_step(const float* __restrict__ xp,
                                                 const float* __restrict__ Whh,
                                                 const float* __restrict__ h_in,
                                                 float* __restrict__ h_out,
                                                 float* __restrict__ cbuf,
                                                 float* __restrict__ hs,
                                                 int t) {
    __shared__ float h_s[16][36];   // stride 36 words: 16B-aligned rows, bank-rotated
    __shared__ float W_s[64][36];
    const int tid = threadIdx.x;
    const int bb = tid >> 4, jj = tid & 15;
    const int b0 = blockIdx.x * 16;
    const int j0 = blockIdx.y * 16;
    float acc[4] = {0.f, 0.f, 0.f, 0.f};

    for (int kc = 0; kc < 512; kc += 32) {
        {
            int r = tid >> 5, col = tid & 31;
            h_s[r][col]     = h_in[(b0 + r) * 512 + kc + col];
            h_s[r + 8][col] = h_in[(b0 + r + 8) * 512 + kc + col];
        }
#pragma unroll
        for (int i = 0; i < 8; ++i) {
            int idx = tid + i * 256;
            int r = idx >> 5, col = idx & 31;
            int n = (r >> 4) * 512 + j0 + (r & 15);   // gate q=r>>4, col j0+(r&15)
            W_s[r][col] = Whh[(size_t)n * 512 + kc + col];
        }
        __syncthreads();
#pragma unroll
        for (int k4 = 0; k4 < 8; ++k4) {
            float4 hv = *(const float4*)&h_s[bb][k4 * 4];
#pragma unroll
            for (int q = 0; q < 4; ++q) {
                float4 wv = *(const float4*)&W_s[q * 16 + jj][k4 * 4];
                acc[q] += hv.x * wv.x + hv.y * wv.y + hv.z * wv.z + hv.w * wv.w;
            }
        }
        __syncthreads();
    }

    const int b = b0 + bb, j = j0 + jj;
    const float* xrow = xp + (size_t)(b * T_DIM + t) * 2048;
    float gi = acc[0] + xrow[j];
    float gf = acc[1] + xrow[512 + j];
    float gg = acc[2] + xrow[1024 + j];
    float go = acc[3] + xrow[1536 + j];
    float si = 1.f / (1.f + expf(-gi));
    float sf = 1.f / (1.f + expf(-gf));
    float tg = tanhf(gg);
    float so = 1.f / (1.f + expf(-go));
    int idx = b * 512 + j;
    float cv = sf * cbuf[idx] + si * tg;
    cbuf[idx] = cv;
    float hv = so * tanhf(cv);
    h_out[idx] = hv;
    hs[(size_t)(b * T_DIM + t) * 512 + j] = hv;
}

// ---------------------------------------------------------------------------
extern "C" void kernel_launch(void* const* d_in, const int* in_sizes, int n_in,
                              void* d_out, int out_size, void* d_ws, size_t ws_size,
                              hipStream_t stream) {
    const int*   sent  = (const int*)d_in[0];
    const float* feat  = (const float*)d_in[1];
    // d_in[2] lengths: unused by reference
    const float* emb   = (const float*)d_in[3];
    const float* W_ih0 = (const float*)d_in[4];
    const float* W_hh0 = (const float*)d_in[5];
    const float* b_ih0 = (const float*)d_in[6];
    const float* b_hh0 = (const float*)d_in[7];
    const float* W_ih1 = (const float*)d_in[8];
    const float* W_hh1 = (const float*)d_in[9];
    const float* b_ih1 = (const float*)d_in[10];
    const float* b_hh1 = (const float*)d_in[11];
    const float* fc_W  = (const float*)d_in[12];
    const float* fc_b  = (const float*)d_in[13];
    float* out = (float*)d_out;
    float* ws  = (float*)d_ws;

    // workspace layout (floats)
    float* x0   = ws;                       // 2048*512      = 1,048,576
    float* xp   = ws + 1048576;             // 2048*2048     = 4,194,304 (shared by both layers)
    float* hs0  = ws + 5242880;             // 2048*512
    float* hs1  = ws + 6291456;             // 2048*512
    float* ha   = ws + 7340032;             // 64*512
    float* cbuf = ws + 7372800;             // 64*512  (adjacent to ha for one memset)
    float* hb   = ws + 7405568;             // 64*512
    // total 7,438,336 floats = 28.4 MB

    build_x<<<dim3(2048), dim3(128), 0, stream>>>(sent, feat, emb, x0);

    // ---- layer 0 ----
    gemm128<0><<<dim3(16, 16), dim3(256), 0, stream>>>(x0, W_ih0, b_ih0, b_hh0, xp, 2048);
    hipMemsetAsync(ha, 0, 2 * 32768 * sizeof(float), stream);   // ha + cbuf
    {
        float* hin = ha; float* hout = hb;
        for (int t = 0; t < T_DIM; ++t) {
            lstm_step<<<dim3(4, 32), dim3(256), 0, stream>>>(xp, W_hh0, hin, hout, cbuf, hs0, t);
            float* tmp = hin; hin = hout; hout = tmp;
        }
    }

    // ---- layer 1 ----
    gemm128<0><<<dim3(16, 16), dim3(256), 0, stream>>>(hs0, W_ih1, b_ih1, b_hh1, xp, 2048);
    hipMemsetAsync(ha, 0, 2 * 32768 * sizeof(float), stream);   // ha + cbuf
    {
        float* hin = ha; float* hout = hb;
        for (int t = 0; t < T_DIM; ++t) {
            lstm_step<<<dim3(4, 32), dim3(256), 0, stream>>>(xp, W_hh1, hin, hout, cbuf, hs1, t);
            float* tmp = hin; hin = hout; hout = tmp;
        }
    }

    // ---- FC to vocab, epilogue writes out[b][v][t] ----
    gemm128<1><<<dim3(16, 250), dim3(256), 0, stream>>>(hs1, fc_W, fc_b, nullptr, out, V_DIM);
}